// Round 1
// baseline (182.958 us; speedup 1.0000x reference)
//
#include <hip/hip_runtime.h>
#include <math.h>

#define NB 16
#define DM 128

__device__ __forceinline__ float softplusf_(float x) {
    // stable: max(x,0) + log1p(exp(-|x|))  (matches jax.nn.softplus)
    return fmaxf(x, 0.0f) + log1pf(expf(-fabsf(x)));
}
__device__ __forceinline__ float sigmoidf_(float x) {
    return 1.0f / (1.0f + expf(-x));
}
__device__ __forceinline__ void softmax16(float* z) {
    float m = z[0];
#pragma unroll
    for (int k = 1; k < NB; k++) m = fmaxf(m, z[k]);
    float s = 0.0f;
#pragma unroll
    for (int k = 0; k < NB; k++) { z[k] = expf(z[k] - m); s += z[k]; }
    float r = 1.0f / s;
#pragma unroll
    for (int k = 0; k < NB; k++) z[k] *= r;
}

__global__ __launch_bounds__(256) void spline_fwd(
    const float* __restrict__ xin, const float* __restrict__ cond,
    const float* __restrict__ Ww, const float* __restrict__ bw,
    const float* __restrict__ Wh, const float* __restrict__ bh,
    const float* __restrict__ Wd, const float* __restrict__ bd,
    const float* __restrict__ Wl, const float* __restrict__ bl,
    float* __restrict__ out, float* __restrict__ lad, int N)
{
    int i = blockIdx.x * 256 + threadIdx.x;
    if (i >= N) return;

    // ---- 4 matvecs: z = W @ cond_row + b  (63 accumulators) ----
    float zw[NB], zh[NB], zl[NB], zd[NB - 1];
#pragma unroll
    for (int k = 0; k < NB; k++) { zw[k] = bw[k]; zh[k] = bh[k]; zl[k] = bl[k]; }
#pragma unroll
    for (int k = 0; k < NB - 1; k++) zd[k] = bd[k];

    const float4* crow = reinterpret_cast<const float4*>(cond) + (size_t)i * (DM / 4);
#pragma unroll 2
    for (int c = 0; c < DM / 4; c++) {
        float4 a = crow[c];
        const int d0 = 4 * c;
#pragma unroll
        for (int k = 0; k < NB; k++) {
            const float* wr = Ww + k * DM + d0;
            zw[k] = fmaf(a.x, wr[0], zw[k]);
            zw[k] = fmaf(a.y, wr[1], zw[k]);
            zw[k] = fmaf(a.z, wr[2], zw[k]);
            zw[k] = fmaf(a.w, wr[3], zw[k]);
        }
#pragma unroll
        for (int k = 0; k < NB; k++) {
            const float* wr = Wh + k * DM + d0;
            zh[k] = fmaf(a.x, wr[0], zh[k]);
            zh[k] = fmaf(a.y, wr[1], zh[k]);
            zh[k] = fmaf(a.z, wr[2], zh[k]);
            zh[k] = fmaf(a.w, wr[3], zh[k]);
        }
#pragma unroll
        for (int k = 0; k < NB - 1; k++) {
            const float* wr = Wd + k * DM + d0;
            zd[k] = fmaf(a.x, wr[0], zd[k]);
            zd[k] = fmaf(a.y, wr[1], zd[k]);
            zd[k] = fmaf(a.z, wr[2], zd[k]);
            zd[k] = fmaf(a.w, wr[3], zd[k]);
        }
#pragma unroll
        for (int k = 0; k < NB; k++) {
            const float* wr = Wl + k * DM + d0;
            zl[k] = fmaf(a.x, wr[0], zl[k]);
            zl[k] = fmaf(a.y, wr[1], zl[k]);
            zl[k] = fmaf(a.z, wr[2], zl[k]);
            zl[k] = fmaf(a.w, wr[3], zl[k]);
        }
    }

    float x = xin[i];
    float xc = fminf(fmaxf(x, -20.0f), 20.0f);

    // ---- widths: module softmax, then spline softmax again ----
    softmax16(zw);
    softmax16(zw);
    const float scale = (1.0f - 1e-3f * NB);
    float cw[NB + 1];
    cw[0] = -20.0f;
    float cum = 0.0f;
#pragma unroll
    for (int k = 0; k < NB; k++) {
        cum += 1e-3f + scale * zw[k];
        cw[k + 1] = 40.0f * cum - 20.0f;
    }
    cw[NB] = 20.0f;

    // ---- searchsorted: idx = sum(xc >= cw[k], k=1..15)  (k=0 always, k=16 never) ----
    int idx = 0;
#pragma unroll
    for (int k = 1; k < NB; k++) idx += (xc >= cw[k]) ? 1 : 0;

    // gather cw[idx], cw[idx+1] via unrolled predicated select (no scratch)
    float in_cw = cw[0], cw_hi = cw[NB];
#pragma unroll
    for (int k = 0; k < NB; k++) {
        if (idx == k) { in_cw = cw[k]; cw_hi = cw[k + 1]; }
    }
    float in_bw = cw_hi - in_cw;

    // ---- heights ----
    softmax16(zh);
    softmax16(zh);
    float ch[NB + 1];
    ch[0] = -20.0f;
    cum = 0.0f;
#pragma unroll
    for (int k = 0; k < NB; k++) {
        cum += 1e-3f + scale * zh[k];
        ch[k + 1] = 40.0f * cum - 20.0f;
    }
    ch[NB] = 20.0f;
    float in_ch = ch[0], ch_hi = ch[NB];
#pragma unroll
    for (int k = 0; k < NB; k++) {
        if (idx == k) { in_ch = ch[k]; ch_hi = ch[k + 1]; }
    }
    float in_h = ch_hi - in_ch;
    float in_delta = in_h / in_bw;

    // ---- derivatives: d = MIN_D + softplus([edge, softplus(zd), edge]) ----
    float zd_lo = 0.0f, zd_hi = 0.0f;
#pragma unroll
    for (int k = 0; k < NB - 1; k++) {
        if (idx - 1 == k) zd_lo = zd[k];
        if (idx == k) zd_hi = zd[k];
    }
    const float cEdge = logf(expf(1.0f - 1e-3f) - 1.0f);
    const float dedge = 1e-3f + softplusf_(cEdge);
    float dk  = (idx == 0)      ? dedge : (1e-3f + softplusf_(softplusf_(zd_lo)));
    float dk1 = (idx == NB - 1) ? dedge : (1e-3f + softplusf_(softplusf_(zd_hi)));

    // ---- lambda: double sigmoid ----
    float zl_sel = zl[0];
#pragma unroll
    for (int k = 0; k < NB; k++) {
        if (idx == k) zl_sel = zl[k];
    }
    float ul = sigmoidf_(zl_sel);
    float lam = 0.95f * sigmoidf_(ul) + 0.025f;

    // ---- rational-linear spline (wa = 1) ----
    float wb = sqrtf(dk / dk1);
    float wc = (lam * dk + (1.0f - lam) * wb * dk1) / in_delta;
    float ya = in_ch;
    float yb = in_h + in_ch;
    float yc = ((1.0f - lam) * ya + lam * wb * yb) / ((1.0f - lam) + lam * wb);
    float theta = (xc - in_cw) / in_bw;
    bool mlt = (theta <= lam);

    float num = mlt ? (ya * (lam - theta) + wc * yc * theta)
                    : (wc * yc * (1.0f - theta) + wb * yb * (theta - lam));
    float den = mlt ? ((lam - theta) + wc * theta)
                    : (wc * (1.0f - theta) + wb * (theta - lam));
    float sout = num / den;
    float dnum = (mlt ? (wc * lam * (yc - ya))
                      : (wb * wc * (1.0f - lam) * (yb - yc))) / in_bw;
    float slad = logf(dnum) - 2.0f * logf(fabsf(den));

    bool inside = (x >= -20.0f) && (x <= 20.0f);
    out[i] = inside ? sout : x;
    lad[i] = inside ? slad : 0.0f;
}

extern "C" void kernel_launch(void* const* d_in, const int* in_sizes, int n_in,
                              void* d_out, int out_size, void* d_ws, size_t ws_size,
                              hipStream_t stream) {
    const float* xin  = (const float*)d_in[0];
    const float* cond = (const float*)d_in[1];
    const float* Ww   = (const float*)d_in[2];
    const float* bwp  = (const float*)d_in[3];
    const float* Wh   = (const float*)d_in[4];
    const float* bhp  = (const float*)d_in[5];
    const float* Wd   = (const float*)d_in[6];
    const float* bdp  = (const float*)d_in[7];
    const float* Wl   = (const float*)d_in[8];
    const float* blp  = (const float*)d_in[9];
    int N = in_sizes[0];  // 32*8192
    float* out = (float*)d_out;
    float* lad = out + N;
    int grid = (N + 255) / 256;
    hipLaunchKernelGGL(spline_fwd, dim3(grid), dim3(256), 0, stream,
                       xin, cond, Ww, bwp, Wh, bhp, Wd, bdp, Wl, blp, out, lad, N);
}

// Round 2
// 49.697 us; speedup vs baseline: 3.6815x; 3.6815x over previous
//
#include <hip/hip_runtime.h>
#include <math.h>

#define NB 16
#define DM 128
#define BM 256
#define ZSTRIDE 68   // halves per Z row: 136 B (8B-aligned for b64 reads, bank-spread writes)

typedef _Float16 half8  __attribute__((ext_vector_type(8)));
typedef _Float16 half4v __attribute__((ext_vector_type(4)));
typedef float    f32x4  __attribute__((ext_vector_type(4)));

__device__ __forceinline__ float softplusf_(float x) {
    return fmaxf(x, 0.0f) + log1pf(expf(-fabsf(x)));
}
__device__ __forceinline__ float sigmoidf_(float x) {
    return 1.0f / (1.0f + expf(-x));
}
__device__ __forceinline__ void softmax16(float* z) {
    float m = z[0];
#pragma unroll
    for (int k = 1; k < NB; k++) m = fmaxf(m, z[k]);
    float s = 0.0f;
#pragma unroll
    for (int k = 0; k < NB; k++) { z[k] = expf(z[k] - m); s += z[k]; }
    float r = 1.0f / s;
#pragma unroll
    for (int k = 0; k < NB; k++) z[k] *= r;
}

__global__ __launch_bounds__(256) void spline_mfma(
    const float* __restrict__ xin, const float* __restrict__ cond,
    const float* __restrict__ Ww, const float* __restrict__ bw,
    const float* __restrict__ Wh, const float* __restrict__ bh,
    const float* __restrict__ Wd, const float* __restrict__ bd,
    const float* __restrict__ Wl, const float* __restrict__ bl,
    float* __restrict__ out, float* __restrict__ lad, int N)
{
    __shared__ __align__(16) _Float16 Z[BM * ZSTRIDE];
    __shared__ float biasS[64];

    const int tid  = threadIdx.x;
    const int wave = tid >> 6;
    const int lane = tid & 63;
    const int l15  = lane & 15;
    const int lg   = lane >> 4;

    // ---- stage biases (N-order: [Ww, Wh, Wl, Wd+pad]) ----
    if (tid < 64) {
        int t = tid >> 4, n = tid & 15;
        float b = 0.0f;
        if (t == 0) b = bw[n];
        else if (t == 1) b = bh[n];
        else if (t == 2) b = bl[n];
        else if (n < 15) b = bd[n];
        biasS[tid] = b;
    }

    // ---- B fragments: W'[64][128] -> 16 frags of 8 f16 each (held in VGPRs) ----
    // B[k][n] = W'[n][k]; lane holds col n = l15, k = 32*s + lg*8 + j
    // (same k<->elem formula used for A below => any HW k-permutation cancels)
    half8 Bf[4][4];
#pragma unroll
    for (int t = 0; t < 4; t++) {
        const float* Wt = (t == 0) ? Ww : (t == 1) ? Wh : (t == 2) ? Wl : Wd;
        const bool valid = (t < 3) || (l15 < 15);
        const float* src = Wt + (size_t)(valid ? l15 : 0) * DM;
#pragma unroll
        for (int s = 0; s < 4; s++) {
            const int k0 = 32 * s + lg * 8;
            half8 f;
            if (valid) {
                float4 a0 = *(const float4*)(src + k0);
                float4 a1 = *(const float4*)(src + k0 + 4);
                f[0] = (_Float16)a0.x; f[1] = (_Float16)a0.y;
                f[2] = (_Float16)a0.z; f[3] = (_Float16)a0.w;
                f[4] = (_Float16)a1.x; f[5] = (_Float16)a1.y;
                f[6] = (_Float16)a1.z; f[7] = (_Float16)a1.w;
            } else {
                f[0]=f[1]=f[2]=f[3]=f[4]=f[5]=f[6]=f[7] = (_Float16)0.0f;
            }
            Bf[t][s] = f;
        }
    }

    const size_t blockRow = (size_t)blockIdx.x * BM;

    // ---- MFMA main: each wave does 4 chunks of 16 rows x 64 cols, K=128 ----
#pragma unroll
    for (int c = 0; c < 4; c++) {
        const int rowInBlk = wave * 64 + c * 16 + l15;
        size_t gr = blockRow + rowInBlk;
        if (gr >= (size_t)N) gr = (size_t)N - 1;
        const float* crow = cond + gr * DM;

        f32x4 acc0 = {0.f,0.f,0.f,0.f}, acc1 = {0.f,0.f,0.f,0.f};
        f32x4 acc2 = {0.f,0.f,0.f,0.f}, acc3 = {0.f,0.f,0.f,0.f};
#pragma unroll
        for (int s = 0; s < 4; s++) {
            const int k0 = 32 * s + lg * 8;
            float4 a0 = *(const float4*)(crow + k0);
            float4 a1 = *(const float4*)(crow + k0 + 4);
            half8 Af;
            Af[0] = (_Float16)a0.x; Af[1] = (_Float16)a0.y;
            Af[2] = (_Float16)a0.z; Af[3] = (_Float16)a0.w;
            Af[4] = (_Float16)a1.x; Af[5] = (_Float16)a1.y;
            Af[6] = (_Float16)a1.z; Af[7] = (_Float16)a1.w;
            acc0 = __builtin_amdgcn_mfma_f32_16x16x32_f16(Af, Bf[0][s], acc0, 0, 0, 0);
            acc1 = __builtin_amdgcn_mfma_f32_16x16x32_f16(Af, Bf[1][s], acc1, 0, 0, 0);
            acc2 = __builtin_amdgcn_mfma_f32_16x16x32_f16(Af, Bf[2][s], acc2, 0, 0, 0);
            acc3 = __builtin_amdgcn_mfma_f32_16x16x32_f16(Af, Bf[3][s], acc3, 0, 0, 0);
        }
        // D layout: col = lane&15, row = (lane>>4)*4 + reg  [measured m89/m91]
        const int zrow = wave * 64 + c * 16 + lg * 4;
#pragma unroll
        for (int r = 0; r < 4; r++) {
            _Float16* zp = &Z[(size_t)(zrow + r) * ZSTRIDE];
            zp[0 * 16 + l15] = (_Float16)acc0[r];
            zp[1 * 16 + l15] = (_Float16)acc1[r];
            zp[2 * 16 + l15] = (_Float16)acc2[r];
            zp[3 * 16 + l15] = (_Float16)acc3[r];
        }
    }

    __syncthreads();

    // ---- epilogue: 1 thread = 1 row ----
    const int r = tid;
    const size_t gi = blockRow + r;
    if (gi >= (size_t)N) return;

    float z[64];
    const half4v* zr4 = (const half4v*)&Z[(size_t)r * ZSTRIDE];
#pragma unroll
    for (int j = 0; j < 16; j++) {
        half4v v = zr4[j];
#pragma unroll
        for (int e = 0; e < 4; e++) z[4 * j + e] = (float)v[e] + biasS[4 * j + e];
    }

    float zw[NB], zh[NB], zl[NB], zd[NB - 1];
#pragma unroll
    for (int k = 0; k < NB; k++) { zw[k] = z[k]; zh[k] = z[16 + k]; zl[k] = z[32 + k]; }
#pragma unroll
    for (int k = 0; k < NB - 1; k++) zd[k] = z[48 + k];

    float x = xin[gi];
    float xc = fminf(fmaxf(x, -20.0f), 20.0f);

    // widths: module softmax, then spline softmax
    softmax16(zw);
    softmax16(zw);
    const float scale = (1.0f - 1e-3f * NB);
    float cw[NB + 1];
    cw[0] = -20.0f;
    float cum = 0.0f;
#pragma unroll
    for (int k = 0; k < NB; k++) {
        cum += 1e-3f + scale * zw[k];
        cw[k + 1] = 40.0f * cum - 20.0f;
    }
    cw[NB] = 20.0f;

    int idx = 0;
#pragma unroll
    for (int k = 1; k < NB; k++) idx += (xc >= cw[k]) ? 1 : 0;

    float in_cw = cw[0], cw_hi = cw[NB];
#pragma unroll
    for (int k = 0; k < NB; k++) {
        if (idx == k) { in_cw = cw[k]; cw_hi = cw[k + 1]; }
    }
    float in_bw = cw_hi - in_cw;

    // heights
    softmax16(zh);
    softmax16(zh);
    float ch[NB + 1];
    ch[0] = -20.0f;
    cum = 0.0f;
#pragma unroll
    for (int k = 0; k < NB; k++) {
        cum += 1e-3f + scale * zh[k];
        ch[k + 1] = 40.0f * cum - 20.0f;
    }
    ch[NB] = 20.0f;
    float in_ch = ch[0], ch_hi = ch[NB];
#pragma unroll
    for (int k = 0; k < NB; k++) {
        if (idx == k) { in_ch = ch[k]; ch_hi = ch[k + 1]; }
    }
    float in_h = ch_hi - in_ch;
    float in_delta = in_h / in_bw;

    // derivatives
    float zd_lo = 0.0f, zd_hi = 0.0f;
#pragma unroll
    for (int k = 0; k < NB - 1; k++) {
        if (idx - 1 == k) zd_lo = zd[k];
        if (idx == k) zd_hi = zd[k];
    }
    const float cEdge = logf(expf(1.0f - 1e-3f) - 1.0f);
    const float dedge = 1e-3f + softplusf_(cEdge);
    float dk  = (idx == 0)      ? dedge : (1e-3f + softplusf_(softplusf_(zd_lo)));
    float dk1 = (idx == NB - 1) ? dedge : (1e-3f + softplusf_(softplusf_(zd_hi)));

    // lambda
    float zl_sel = zl[0];
#pragma unroll
    for (int k = 0; k < NB; k++) {
        if (idx == k) zl_sel = zl[k];
    }
    float ul = sigmoidf_(zl_sel);
    float lam = 0.95f * sigmoidf_(ul) + 0.025f;

    // rational-linear spline (wa = 1)
    float wb = sqrtf(dk / dk1);
    float wc = (lam * dk + (1.0f - lam) * wb * dk1) / in_delta;
    float ya = in_ch;
    float yb = in_h + in_ch;
    float yc = ((1.0f - lam) * ya + lam * wb * yb) / ((1.0f - lam) + lam * wb);
    float theta = (xc - in_cw) / in_bw;
    bool mlt = (theta <= lam);

    float num = mlt ? (ya * (lam - theta) + wc * yc * theta)
                    : (wc * yc * (1.0f - theta) + wb * yb * (theta - lam));
    float den = mlt ? ((lam - theta) + wc * theta)
                    : (wc * (1.0f - theta) + wb * (theta - lam));
    float sout = num / den;
    float dnum = (mlt ? (wc * lam * (yc - ya))
                      : (wb * wc * (1.0f - lam) * (yb - yc))) / in_bw;
    float slad = logf(dnum) - 2.0f * logf(fabsf(den));

    bool inside = (x >= -20.0f) && (x <= 20.0f);
    out[gi] = inside ? sout : x;
    lad[gi] = inside ? slad : 0.0f;
}

extern "C" void kernel_launch(void* const* d_in, const int* in_sizes, int n_in,
                              void* d_out, int out_size, void* d_ws, size_t ws_size,
                              hipStream_t stream) {
    const float* xin  = (const float*)d_in[0];
    const float* cond = (const float*)d_in[1];
    const float* Ww   = (const float*)d_in[2];
    const float* bwp  = (const float*)d_in[3];
    const float* Wh   = (const float*)d_in[4];
    const float* bhp  = (const float*)d_in[5];
    const float* Wd   = (const float*)d_in[6];
    const float* bdp  = (const float*)d_in[7];
    const float* Wl   = (const float*)d_in[8];
    const float* blp  = (const float*)d_in[9];
    int N = in_sizes[0];  // 32*8192
    float* out = (float*)d_out;
    float* lad = out + N;
    int grid = (N + BM - 1) / BM;
    hipLaunchKernelGGL(spline_mfma, dim3(grid), dim3(256), 0, stream,
                       xin, cond, Ww, bwp, Wh, bhp, Wd, bdp, Wl, blp, out, lad, N);
}

// Round 4
// 43.317 us; speedup vs baseline: 4.2237x; 1.1473x over previous
//
#include <hip/hip_runtime.h>
#include <math.h>

#define NB 16
#define DM 128
#define BM 256
#define ZSTRIDE 68   // halves per Z row: 136 B (8B-aligned for b64 reads)

typedef _Float16 half8  __attribute__((ext_vector_type(8)));
typedef _Float16 half4v __attribute__((ext_vector_type(4)));
typedef _Float16 half2v __attribute__((ext_vector_type(2)));
typedef __fp16   fp16x2 __attribute__((ext_vector_type(2)));
typedef float    f32x4  __attribute__((ext_vector_type(4)));

__device__ __forceinline__ float frcp_(float x) { return __builtin_amdgcn_rcpf(x); }
__device__ __forceinline__ float softplus_fast(float x) {
    // max(x,0) + log(1+exp(-|x|)); arg of log in [1,2] -> native log fine
    return fmaxf(x, 0.0f) + __logf(1.0f + __expf(-fabsf(x)));
}
__device__ __forceinline__ float sigmoid_fast(float x) {
    return frcp_(1.0f + __expf(-x));
}
// inner softmax (with max-subtract for safety)
__device__ __forceinline__ void softmax16_m(float* z) {
    float m = z[0];
#pragma unroll
    for (int k = 1; k < NB; k++) m = fmaxf(m, z[k]);
    float s = 0.0f;
#pragma unroll
    for (int k = 0; k < NB; k++) { z[k] = __expf(z[k] - m); s += z[k]; }
    float r = frcp_(s);
#pragma unroll
    for (int k = 0; k < NB; k++) z[k] *= r;
}
// outer softmax: inputs in [0,1] (output of inner softmax) -> no max needed
__device__ __forceinline__ void softmax16_nm(float* z) {
    float s = 0.0f;
#pragma unroll
    for (int k = 0; k < NB; k++) { z[k] = __expf(z[k]); s += z[k]; }
    float r = frcp_(s);
#pragma unroll
    for (int k = 0; k < NB; k++) z[k] *= r;
}

__device__ __forceinline__ half2v pk_(float lo, float hi) {
    fp16x2 p = __builtin_amdgcn_cvt_pkrtz(lo, hi);
    return __builtin_bit_cast(half2v, p);
}
__device__ __forceinline__ half8 cvt8(float4 a0, float4 a1) {
    half2v p0 = pk_(a0.x, a0.y);
    half2v p1 = pk_(a0.z, a0.w);
    half2v p2 = pk_(a1.x, a1.y);
    half2v p3 = pk_(a1.z, a1.w);
    half8 f;
    f[0] = p0[0]; f[1] = p0[1]; f[2] = p1[0]; f[3] = p1[1];
    f[4] = p2[0]; f[5] = p2[1]; f[6] = p3[0]; f[7] = p3[1];
    return f;
}

__global__ __launch_bounds__(256, 4) void spline_mfma(
    const float* __restrict__ xin, const float* __restrict__ cond,
    const float* __restrict__ Ww, const float* __restrict__ bw,
    const float* __restrict__ Wh, const float* __restrict__ bh,
    const float* __restrict__ Wd, const float* __restrict__ bd,
    const float* __restrict__ Wl, const float* __restrict__ bl,
    float* __restrict__ out, float* __restrict__ lad, int N)
{
    __shared__ __align__(16) _Float16 Z[BM * ZSTRIDE];

    const int tid  = threadIdx.x;
    const int wave = tid >> 6;
    const int lane = tid & 63;
    const int l15  = lane & 15;
    const int lg   = lane >> 4;

    // ---- B fragments: W'[64][128] -> 16 frags of 8 f16 (VGPR-resident) ----
    // B[k][n] = W'[n][k]; lane holds col n=l15, k = 32*s + lg*8 + j
    // (identical k<->elem formula as A below => HW k-permutation cancels)
    half8 Bf[4][4];
#pragma unroll
    for (int t = 0; t < 4; t++) {
        const float* Wt = (t == 0) ? Ww : (t == 1) ? Wh : (t == 2) ? Wl : Wd;
        const bool valid = (t < 3) || (l15 < 15);
        const float* src = Wt + (size_t)(valid ? l15 : 0) * DM;
#pragma unroll
        for (int s = 0; s < 4; s++) {
            const int k0 = 32 * s + lg * 8;
            if (valid) {
                float4 a0 = *(const float4*)(src + k0);
                float4 a1 = *(const float4*)(src + k0 + 4);
                Bf[t][s] = cvt8(a0, a1);
            } else {
                half8 f;
                f[0]=f[1]=f[2]=f[3]=f[4]=f[5]=f[6]=f[7] = (_Float16)0.0f;
                Bf[t][s] = f;
            }
        }
    }

    const size_t blockRow = (size_t)blockIdx.x * BM;

    // ---- MFMA main: wave-local. Each wave: 4 chunks of 16 rows x 64 cols ----
#pragma unroll
    for (int c = 0; c < 4; c++) {
        const int rowInBlk = wave * 64 + c * 16 + l15;
        size_t gr = blockRow + rowInBlk;
        if (gr >= (size_t)N) gr = (size_t)N - 1;
        const float* crow = cond + gr * DM;

        f32x4 acc0 = {0.f,0.f,0.f,0.f}, acc1 = {0.f,0.f,0.f,0.f};
        f32x4 acc2 = {0.f,0.f,0.f,0.f}, acc3 = {0.f,0.f,0.f,0.f};
#pragma unroll
        for (int s = 0; s < 4; s++) {
            const int k0 = 32 * s + lg * 8;
            float4 a0 = *(const float4*)(crow + k0);
            float4 a1 = *(const float4*)(crow + k0 + 4);
            half8 Af = cvt8(a0, a1);
            acc0 = __builtin_amdgcn_mfma_f32_16x16x32_f16(Af, Bf[0][s], acc0, 0, 0, 0);
            acc1 = __builtin_amdgcn_mfma_f32_16x16x32_f16(Af, Bf[1][s], acc1, 0, 0, 0);
            acc2 = __builtin_amdgcn_mfma_f32_16x16x32_f16(Af, Bf[2][s], acc2, 0, 0, 0);
            acc3 = __builtin_amdgcn_mfma_f32_16x16x32_f16(Af, Bf[3][s], acc3, 0, 0, 0);
        }
        // D layout: col = lane&15, row = (lane>>4)*4 + reg  [m89/m91]
        const int zrow = wave * 64 + c * 16 + lg * 4;
#pragma unroll
        for (int r = 0; r < 4; r++) {
            _Float16* zp = &Z[(size_t)(zrow + r) * ZSTRIDE];
            zp[0 * 16 + l15] = (_Float16)acc0[r];
            zp[1 * 16 + l15] = (_Float16)acc1[r];
            zp[2 * 16 + l15] = (_Float16)acc2[r];
            zp[3 * 16 + l15] = (_Float16)acc3[r];
        }
    }

    // Wave-local LDS dependency only (wave w writes rows [64w,64w+64), thread
    // tid reads row tid of its own wave) -> no __syncthreads; drain DS queue.
    __builtin_amdgcn_sched_barrier(0);
    asm volatile("s_waitcnt lgkmcnt(0)" ::: "memory");
    __builtin_amdgcn_sched_barrier(0);

    // ---- epilogue: 1 thread = 1 row ----
    const int r = tid;
    const size_t gi = blockRow + r;
    if (gi >= (size_t)N) return;

    float x = xin[gi];

    float z[64];
    const half4v* zr4 = (const half4v*)&Z[(size_t)r * ZSTRIDE];
#pragma unroll
    for (int j = 0; j < 16; j++) {
        half4v v = zr4[j];
#pragma unroll
        for (int e = 0; e < 4; e++) z[4 * j + e] = (float)v[e];
    }

    float zw[NB], zh[NB], zl[NB], zd[NB - 1];
#pragma unroll
    for (int k = 0; k < NB; k++) {
        zw[k] = z[k]      + bw[k];   // wave-uniform s_loads
        zh[k] = z[16 + k] + bh[k];
        zl[k] = z[32 + k] + bl[k];
    }
#pragma unroll
    for (int k = 0; k < NB - 1; k++) zd[k] = z[48 + k] + bd[k];

    float xc = fminf(fmaxf(x, -20.0f), 20.0f);

    // widths: module softmax, then spline softmax
    softmax16_m(zw);
    softmax16_nm(zw);
    const float scale = (1.0f - 1e-3f * NB);
    float cw[NB + 1];
    cw[0] = -20.0f;
    float cum = 0.0f;
#pragma unroll
    for (int k = 0; k < NB; k++) {
        cum += 1e-3f + scale * zw[k];
        cw[k + 1] = 40.0f * cum - 20.0f;
    }
    cw[NB] = 20.0f;

    int idx = 0;
#pragma unroll
    for (int k = 1; k < NB; k++) idx += (xc >= cw[k]) ? 1 : 0;

    float in_cw = cw[0], cw_hi = cw[NB];
#pragma unroll
    for (int k = 0; k < NB; k++) {
        if (idx == k) { in_cw = cw[k]; cw_hi = cw[k + 1]; }
    }
    float in_bw = cw_hi - in_cw;

    // heights
    softmax16_m(zh);
    softmax16_nm(zh);
    float ch[NB + 1];
    ch[0] = -20.0f;
    cum = 0.0f;
#pragma unroll
    for (int k = 0; k < NB; k++) {
        cum += 1e-3f + scale * zh[k];
        ch[k + 1] = 40.0f * cum - 20.0f;
    }
    ch[NB] = 20.0f;
    float in_ch = ch[0], ch_hi = ch[NB];
#pragma unroll
    for (int k = 0; k < NB; k++) {
        if (idx == k) { in_ch = ch[k]; ch_hi = ch[k + 1]; }
    }
    float in_h = ch_hi - in_ch;

    // derivatives: d = MIN_D + softplus([edge, softplus(zd), edge])
    float zd_lo = 0.0f, zd_hi = 0.0f;
#pragma unroll
    for (int k = 0; k < NB - 1; k++) {
        if (idx - 1 == k) zd_lo = zd[k];
        if (idx == k) zd_hi = zd[k];
    }
    const float dedge = 1.0f;  // 1e-3 + softplus(log(exp(1-1e-3)-1)) == 1.0 exactly
    float dk  = (idx == 0)      ? dedge : (1e-3f + softplus_fast(softplus_fast(zd_lo)));
    float dk1 = (idx == NB - 1) ? dedge : (1e-3f + softplus_fast(softplus_fast(zd_hi)));

    // lambda
    float zl_sel = zl[0];
#pragma unroll
    for (int k = 0; k < NB; k++) {
        if (idx == k) zl_sel = zl[k];
    }
    float ul = sigmoid_fast(zl_sel);
    float lam = 0.95f * sigmoid_fast(ul) + 0.025f;

    // rational-linear spline (wa = 1)
    float rbw = frcp_(in_bw);
    float in_delta = in_h * rbw;
    float wb = sqrtf(dk * frcp_(dk1));
    float wc = (lam * dk + (1.0f - lam) * wb * dk1) * frcp_(in_delta);
    float ya = in_ch;
    float yb = in_h + in_ch;
    float yc = ((1.0f - lam) * ya + lam * wb * yb) * frcp_((1.0f - lam) + lam * wb);
    float theta = (xc - in_cw) * rbw;
    bool mlt = (theta <= lam);

    float num = mlt ? (ya * (lam - theta) + wc * yc * theta)
                    : (wc * yc * (1.0f - theta) + wb * yb * (theta - lam));
    float den = mlt ? ((lam - theta) + wc * theta)
                    : (wc * (1.0f - theta) + wb * (theta - lam));
    float sout = num * frcp_(den);
    float dnum = (mlt ? (wc * lam * (yc - ya))
                      : (wb * wc * (1.0f - lam) * (yb - yc))) * rbw;
    float slad = __logf(dnum) - 2.0f * __logf(fabsf(den));

    bool inside = (x >= -20.0f) && (x <= 20.0f);
    out[gi] = inside ? sout : x;
    lad[gi] = inside ? slad : 0.0f;
}

extern "C" void kernel_launch(void* const* d_in, const int* in_sizes, int n_in,
                              void* d_out, int out_size, void* d_ws, size_t ws_size,
                              hipStream_t stream) {
    const float* xin  = (const float*)d_in[0];
    const float* cond = (const float*)d_in[1];
    const float* Ww   = (const float*)d_in[2];
    const float* bwp  = (const float*)d_in[3];
    const float* Wh   = (const float*)d_in[4];
    const float* bhp  = (const float*)d_in[5];
    const float* Wd   = (const float*)d_in[6];
    const float* bdp  = (const float*)d_in[7];
    const float* Wl   = (const float*)d_in[8];
    const float* blp  = (const float*)d_in[9];
    int N = in_sizes[0];  // 32*8192
    float* out = (float*)d_out;
    float* lad = out + N;
    int grid = (N + BM - 1) / BM;
    hipLaunchKernelGGL(spline_mfma, dim3(grid), dim3(256), 0, stream,
                       xin, cond, Ww, bwp, Wh, bhp, Wd, bdp, Wl, blp, out, lad, N);
}